// Round 17
// baseline (327.987 us; speedup 1.0000x reference)
//
#include <hip/hip_runtime.h>

#define EPSF 1e-8f

typedef __attribute__((ext_vector_type(8))) short bf16x8;
typedef __attribute__((ext_vector_type(16))) float f32x16;

#define MFMA32(a, b, c) __builtin_amdgcn_mfma_f32_32x32x16_bf16(a, b, c, 0, 0, 0)

// split f32 into (hi bf16 | lo bf16) packed in one u32: low16 = hi-part, high16 = lo-part
__device__ __forceinline__ uint32_t splitpack(float v) {
    uint32_t u = __float_as_uint(v);
    uint32_t hb = (u + 0x7fffu + ((u >> 16) & 1u)) & 0xffff0000u;  // RNE bf16 of v (f32 bits)
    float rem = v - __uint_as_float(hb);
    uint32_t r = __float_as_uint(rem);
    uint32_t lb = (r + 0x7fffu + ((r >> 16) & 1u)) >> 16;          // RNE bf16 of remainder
    return (hb >> 16) | (lb << 16);
}
__device__ __forceinline__ float unpackf(uint32_t p) {
    return __uint_as_float(p << 16) + __uint_as_float(p & 0xffff0000u);
}

// async global->LDS, 16B per lane; dst passed per-lane (base + lane*16) consistent with HW.
__device__ __forceinline__ void gload_lds16(const void* src, void* dst) {
#if __has_builtin(__builtin_amdgcn_global_load_lds)
    __builtin_amdgcn_global_load_lds(
        (const __attribute__((address_space(1))) uint32_t*)src,
        (__attribute__((address_space(3))) uint32_t*)dst, 16, 0, 0);
#else
    *(uint4*)dst = *(const uint4*)src;
#endif
}

// ---------- x [16][128][64][64] f32 -> hi/lo bf16 planes, frag-friendly layout ----------
// xph/xpl index: (((b*16 + cg)*64 + h)*64 + w)*8 + j   (cg = c/8, j = c%8)
__global__ __launch_bounds__(256) void k_xpack(const float* __restrict__ x,
                                               unsigned short* __restrict__ xph,
                                               unsigned short* __restrict__ xpl) {
    const int bx = blockIdx.x;                 // 4096 = b16 * cg16 * hb16
    const int hb = bx & 15, cg = (bx >> 4) & 15, b = bx >> 8;
    const int tid = threadIdx.x;
    const int w = tid & 63, hs = tid >> 6;
    const int h = hb * 4 + hs;
    uint32_t hiw[4], low[4];
#pragma unroll
    for (int q = 0; q < 4; ++q) {
        uint32_t u0 = splitpack(x[(((b * 128 + cg * 8 + q * 2) * 64) + h) * 64 + w]);
        uint32_t u1 = splitpack(x[(((b * 128 + cg * 8 + q * 2 + 1) * 64) + h) * 64 + w]);
        hiw[q] = (u0 & 0xffffu) | (u1 << 16);
        low[q] = (u0 >> 16) | (u1 & 0xffff0000u);
    }
    const long o = ((((long)(b * 16 + cg) * 64 + h) * 64) + w) * 8;
    *(uint4*)(xph + o) = *(uint4*)hiw;
    *(uint4*)(xpl + o) = *(uint4*)low;
}

// ---------- pack w1 into 32x32x16 B-frag order: [tap9][cp8][ntile8][lane64][j8] ----------
__global__ __launch_bounds__(256) void k_wpack(const float* __restrict__ w1,
                                               short* __restrict__ Bh, short* __restrict__ Bl) {
    int d = blockIdx.x * 256 + threadIdx.x;    // 294912
    int j = d & 7, lane = (d >> 3) & 63, nt = (d >> 9) & 7, cp = (d >> 12) & 7, tap = d >> 15;
    int oc = nt * 32 + (lane & 31);
    int cin = cp * 16 + (lane >> 5) * 8 + j;
    uint32_t u = splitpack(w1[oc * 1152 + cin * 9 + tap]);
    Bh[d] = (short)(u & 0xffffu);
    Bl[d] = (short)(u >> 16);
}

// ---------- conv1: 3x3 SAME, bf16x3 via 32x32x16 MFMA ----------
// block: 512 thr = 8 waves (4 mq x 2 og); tile 256 pixels (4h x 64w) x 256 oc (full).
// wave = 64p x 128oc: acc[2][4] = 128 AGPR -> 24 MFMA/tap/wave, but per-wave A-reads
// stay at 4/tap (r14's proven value). Per-tap/block: 32 LDS b128 (~385cy) vs 384 MFMA cy
// -> balanced 1:1 (r16's 2mq x 4og was 2:1 LDS-bound from 4x duplicated A-reads).
// 1 block/CU, grid 256 (single round; B L2 traffic and LDS totals both halved vs r14).
// B 2-buf, 1-tap lead + parity-clean seam tap-0 prefetch. A JIT ds_read.
// XCD remap: 32 contiguous blocks per XCD.
// LDS: 2buf x 2plane x 12units(row6 x kg2) x 66wl x 16B = 50688 B.
__global__ __launch_bounds__(512, 2) void k_conv1(
        const unsigned short* __restrict__ xph, const unsigned short* __restrict__ xpl,
        const short* __restrict__ Bh, const short* __restrict__ Bl,
        const float* __restrict__ b1,
        uint32_t* __restrict__ c1p, float* __restrict__ gpart) {
    __shared__ uint4 lds[2 * 2 * 12 * 66];
    const int bxr = blockIdx.x;                // 256; remap so XCD k gets [k*32,(k+1)*32)
    const int bx = ((bxr & 7) << 5) | (bxr >> 3);
    const int hp = bx & 15, b = bx >> 4;
    const int h0 = hp * 4;
    const int tid = threadIdx.x;
    const int lane = tid & 63, wv = tid >> 6;  // 8 waves
    const int mq = wv >> 1, og = wv & 1;       // 4 h-rows x 2 oc-halves
    const int l31 = lane & 31, hbit = lane >> 5;

    f32x16 acc[2][4];
#pragma unroll
    for (int i = 0; i < 2; ++i)
#pragma unroll
        for (int j = 0; j < 4; ++j)
#pragma unroll
            for (int r = 0; r < 16; ++r) acc[i][j][r] = 0.f;

    auto stage = [&](int buf, int cp) {
#pragma unroll
        for (int i = 0; i < 3; ++i) {
            const int id = wv * 3 + i;              // 0..23
            const int plane = (id >= 12) ? 1 : 0;
            const int u = id - plane * 12;          // 0..11
            const int r6 = u >> 1, kg = u & 1;
            const int grow = h0 - 1 + r6;
            uint4* dst = &lds[((buf * 2 + plane) * 12 + u) * 66 + 1 + lane];
            if ((unsigned)grow < 64u) {
                const unsigned short* pls = plane ? xpl : xph;
                const unsigned short* src =
                    pls + ((((long)(b * 16 + cp * 2 + kg) * 64 + grow) * 64) + lane) * 8;
                gload_lds16(src, dst);
            } else {
                *dst = (uint4){0u, 0u, 0u, 0u};
            }
        }
    };

    stage(0, 0);
    if (tid < 96) {   // halo zeros (wl = 0, 65) for all buf/plane/units
        const int row = tid >> 1, side = tid & 1;
        lds[row * 66 + (side ? 65 : 0)] = (uint4){0u, 0u, 0u, 0u};
    }
    __syncthreads();

    bf16x8 Bhv[2][4], Blv[2][4];
#define LOADB(cp_, tap_, par) do {                                                \
        _Pragma("unroll")                                                         \
        for (int nt = 0; nt < 4; ++nt) {                                          \
            const int fi = (((tap_) * 8 + (cp_)) * 8 + og * 4 + nt) * 512 + lane * 8; \
            Bhv[par][nt] = *(const bf16x8*)(Bh + fi);                             \
            Blv[par][nt] = *(const bf16x8*)(Bl + fi);                             \
        } } while (0)

    LOADB(0, 0, 0);
    int buf = 0;
    for (int cp = 0; cp < 8; ++cp) {
        if (cp < 7) stage(buf ^ 1, cp + 1);
#pragma unroll
        for (int tap = 0; tap < 9; ++tap) {
            if (tap < 8) LOADB(cp, tap + 1, (tap + 1) & 1);
            const int kh = tap / 3, kw = tap % 3;
            bf16x8 ah[2], al[2];
#pragma unroll
            for (int mt = 0; mt < 2; ++mt) {
                const int rb = ((buf * 2 + 0) * 12 + (mq + kh) * 2 + hbit) * 66
                               + kw + mt * 32 + l31;
                ah[mt] = *(const bf16x8*)&lds[rb];
                al[mt] = *(const bf16x8*)&lds[rb + 12 * 66];
            }
            const int par = tap & 1;
            __builtin_amdgcn_s_setprio(1);
#pragma unroll
            for (int nt = 0; nt < 4; ++nt)
#pragma unroll
                for (int mt = 0; mt < 2; ++mt) {
                    acc[mt][nt] = MFMA32(ah[mt], Bhv[par][nt], acc[mt][nt]);
                    acc[mt][nt] = MFMA32(ah[mt], Blv[par][nt], acc[mt][nt]);
                    acc[mt][nt] = MFMA32(al[mt], Bhv[par][nt], acc[mt][nt]);
                }
            __builtin_amdgcn_s_setprio(0);
            if (tap == 8 && cp < 7) LOADB(cp + 1, 0, 0);   // seam: par0 free after tap8
        }
        __syncthreads();
        buf ^= 1;
    }
#undef LOADB

    const int hrow = h0 + mq;
#pragma unroll
    for (int nt = 0; nt < 4; ++nt) {
        const int oc = og * 128 + nt * 32 + l31;
        float g = 0.f;
#pragma unroll
        for (int mt = 0; mt < 2; ++mt)
#pragma unroll
            for (int r = 0; r < 16; ++r) g += acc[mt][nt][r];
        g += __shfl_xor(g, 32);
        if (hbit == 0) gpart[((b * 16 + hp) * 4 + mq) * 256 + oc] = g;
        const float bias = b1[oc];
#pragma unroll
        for (int mt = 0; mt < 2; ++mt) {
#pragma unroll
            for (int r = 0; r < 16; ++r) {
                const int row = (r & 3) + 8 * (r >> 2) + 4 * hbit;
                const int p = hrow * 64 + mt * 32 + row;
                c1p[((long)(b * 4096 + p)) * 256 + oc] = splitpack(acc[mt][nt][r] + bias);
            }
        }
    }
}

// ---------- tiny MLP chain: sum gap partials, c2, c3 -> scale, ga, n_g ----------
__global__ __launch_bounds__(256) void k_mlp(const float* __restrict__ gpart,
                                             const float* __restrict__ b1,
                                             const float* __restrict__ w2, const float* __restrict__ b2,
                                             const float* __restrict__ w3, const float* __restrict__ b3,
                                             float* __restrict__ scale, float* __restrict__ ga,
                                             float* __restrict__ n_g) {
    int b = blockIdx.x, tid = threadIdx.x;
    __shared__ float gs[256], c2s[256], red[4];
    float g = 0.f;
#pragma unroll 8
    for (int i = 0; i < 64; ++i) g += gpart[(b * 64 + i) * 256 + tid];
    gs[tid] = g * (1.f / 4096.f) + b1[tid];
    __syncthreads();
    {
        const float4* wr = (const float4*)(w2 + tid * 256);
        float a = b2[tid];
#pragma unroll 8
        for (int c4 = 0; c4 < 64; c4++) {
            float4 wv = wr[c4];
            a += wv.x * gs[c4*4] + wv.y * gs[c4*4+1] + wv.z * gs[c4*4+2] + wv.w * gs[c4*4+3];
        }
        c2s[tid] = a;
    }
    __syncthreads();
    float a3 = b3[tid];
    {
        const float4* wr = (const float4*)(w3 + tid * 256);
#pragma unroll 8
        for (int c4 = 0; c4 < 64; c4++) {
            float4 wv = wr[c4];
            a3 += wv.x * c2s[c4*4] + wv.y * c2s[c4*4+1] + wv.z * c2s[c4*4+2] + wv.w * c2s[c4*4+3];
        }
    }
    float s1 = 1.f + a3;
    float g2 = gs[tid] * s1;
    scale[b * 256 + tid] = s1;
    ga[b * 256 + tid] = g2 * s1;
    float r = g2 * g2;
    for (int off = 32; off; off >>= 1) r += __shfl_down(r, off);
    if ((tid & 63) == 0) red[tid >> 6] = r;
    __syncthreads();
    if (tid == 0) n_g[b] = fmaxf(sqrtf(red[0] + red[1] + red[2] + red[3]), EPSF);
}

// ---------- cos -> r1[b][p], packed NHWC reads, 32-lane reduce per pixel ----------
__global__ __launch_bounds__(256) void k_cos(
        const uint32_t* __restrict__ c1p,
        const float* __restrict__ scale, const float* __restrict__ ga,
        const float* __restrict__ n_g, float* __restrict__ r1) {
    const int bx = blockIdx.x;                 // 1024 = b16 * pt64
    const int pt = bx & 63, b = bx >> 6;
    const int tid = threadIdx.x;
    const int lane = tid & 63, wv = tid >> 6;
    const int half = lane >> 5, l31 = lane & 31;
    float ga8[8], sc8[8];
#pragma unroll
    for (int q = 0; q < 8; ++q) {
        ga8[q] = ga[b * 256 + l31 * 8 + q];
        sc8[q] = scale[b * 256 + l31 * 8 + q];
    }
    const float ng = n_g[b];
#pragma unroll
    for (int pp = 0; pp < 8; ++pp) {
        const int p = pt * 64 + wv * 16 + pp * 2 + half;
        const uint32_t* base = c1p + ((long)(b * 4096 + p)) * 256 + l31 * 8;
        uint4 a = *(const uint4*)base;
        uint4 bq = *(const uint4*)(base + 4);
        uint32_t pk[8] = {a.x, a.y, a.z, a.w, bq.x, bq.y, bq.z, bq.w};
        float num = 0.f, den = 0.f;
#pragma unroll
        for (int q = 0; q < 8; ++q) {
            const float v = unpackf(pk[q]);
            num += ga8[q] * v;
            const float t = sc8[q] * v;
            den += t * t;
        }
#pragma unroll
        for (int off = 1; off <= 16; off <<= 1) {
            num += __shfl_xor(num, off);
            den += __shfl_xor(den, off);
        }
        if (l31 == 0) {
            float na = fmaxf(sqrtf(den), EPSF);
            r1[b * 4096 + p] = num / (ng * na);
        }
    }
}

// ---------- U-factor: Uf[b'][pr*256+k] = sum_o w4[o][k]*r1[b'][pr*256+o]; Dpart[b'*16+pr] ----------
__global__ __launch_bounds__(256) void k_u(const float* __restrict__ r1,
                                           const float* __restrict__ w4,
                                           const float* __restrict__ b4,
                                           float* __restrict__ Uf, float* __restrict__ Dpart) {
    const int g = blockIdx.x;                  // 256 = b'16 * pr16
    const int tid = threadIdx.x;
    __shared__ float rs[256], red[4];
    rs[tid] = r1[(g >> 4) * 4096 + (g & 15) * 256 + tid];
    __syncthreads();
    float a = 0.f;
#pragma unroll 8
    for (int o = 0; o < 256; ++o) a += rs[o] * w4[o * 256 + tid];
    Uf[(g >> 4) * 4096 + (g & 15) * 256 + tid] = a;
    float d = b4[tid] * rs[tid];
    for (int off = 32; off; off >>= 1) d += __shfl_down(d, off);
    if ((tid & 63) == 0) red[tid >> 6] = d;
    __syncthreads();
    if (tid == 0) Dpart[g] = red[0] + red[1] + red[2] + red[3];
}

// ---------- t slice: tmat4[kc][b][i][b'] = sum_{jc in kc} c1s[b][i][jj]*Uf[b'][jj] (+D on kc0) ----------
// split-K x4 for occupancy: 1024 blocks (4/CU) instead of 256.
__global__ __launch_bounds__(256) void k_t2(const uint32_t* __restrict__ c1p,
                                            const float* __restrict__ Uf,
                                            const float* __restrict__ scale,
                                            const float* __restrict__ Dpart,
                                            float* __restrict__ tmat4) {
    __shared__ float Ac[16][256];
    __shared__ float Bc[16][260];
    __shared__ float scs[256];
    const int bx = blockIdx.x;                 // 1024 = kc4 * b16 * it16
    const int kc = bx >> 8;
    const int b = (bx >> 4) & 15, it = bx & 15;
    const int tid = threadIdx.x;
    const int il = tid >> 4, bp = tid & 15;
    scs[tid] = scale[b * 256 + tid];
    float acc = 0.f;
    for (int jc = kc * 4; jc < kc * 4 + 4; ++jc) {   // chunk: pr = jc, k in [0,256)
        __syncthreads();
#pragma unroll
        for (int q = 0; q < 4; ++q) {
            const int f4i = tid + q * 256;
            const int row = f4i >> 6, col4 = f4i & 63;
            uint4 u = *(const uint4*)(c1p +
                ((long)(b * 4096 + it * 256 + row * 16 + jc)) * 256 + col4 * 4);
            Ac[row][col4 * 4 + 0] = unpackf(u.x) * scs[col4 * 4 + 0];
            Ac[row][col4 * 4 + 1] = unpackf(u.y) * scs[col4 * 4 + 1];
            Ac[row][col4 * 4 + 2] = unpackf(u.z) * scs[col4 * 4 + 2];
            Ac[row][col4 * 4 + 3] = unpackf(u.w) * scs[col4 * 4 + 3];
            *(float4*)&Bc[row][col4 * 4] =
                *(const float4*)(Uf + (long)row * 4096 + jc * 256 + col4 * 4);
        }
        __syncthreads();
#pragma unroll 8
        for (int j = 0; j < 256; j += 4) {
            float4 a4  = *(const float4*)&Ac[il][j];
            float4 b4v = *(const float4*)&Bc[bp][j];
            acc += a4.x * b4v.x + a4.y * b4v.y + a4.z * b4v.z + a4.w * b4v.w;
        }
    }
    if (kc == 0) {
        float D = 0.f;
#pragma unroll
        for (int pr = 0; pr < 16; ++pr) D += Dpart[bp * 16 + pr];
        acc += D;
    }
    tmat4[kc * 65536 + ((b * 256) + it * 16 + il) * 16 + bp] = acc;
}

// ---------- m2[b][i][p] = sum_b' t[b][i][b'] * r1[b'][p]  (writes d_out) ----------
__global__ __launch_bounds__(256) void k_m2(const float* __restrict__ tmat4,
                                            const float* __restrict__ r1,
                                            float* __restrict__ outb) {
    __shared__ float r1s[16][512];
    __shared__ float ts[256];
    int bx = blockIdx.x;
    int b = bx >> 7, it = (bx >> 3) & 15, pc = bx & 7;
    int tid = threadIdx.x;
    {
        const int idx = (b * 256 + it * 16) * 16 + tid;
        ts[tid] = tmat4[idx] + tmat4[65536 + idx] + tmat4[131072 + idx] + tmat4[196608 + idx];
    }
#pragma unroll
    for (int k = 0; k < 8; k++) {
        int f4i = tid + k * 256;
        int row = f4i >> 7, col = f4i & 127;
        *(float4*)&r1s[row][col * 4] = *(const float4*)(r1 + ((long)row << 12) + pc * 512 + col * 4);
    }
    __syncthreads();
    for (int il = 0; il < 16; il++) {
        float tv[16];
#pragma unroll
        for (int bp = 0; bp < 16; bp++) tv[bp] = ts[il * 16 + bp];
#pragma unroll
        for (int k = 0; k < 2; k++) {
            int p = k * 256 + tid;
            float s = 0.f;
#pragma unroll
            for (int bp = 0; bp < 16; bp++) s += tv[bp] * r1s[bp][p];
            outb[((long)b << 20) + ((long)(it * 16 + il) << 12) + pc * 512 + p] = s;
        }
    }
}

extern "C" void kernel_launch(void* const* d_in, const int* in_sizes, int n_in,
                              void* d_out, int out_size, void* d_ws, size_t ws_size,
                              hipStream_t stream) {
    const float* x  = (const float*)d_in[0];
    const float* w1 = (const float*)d_in[1];
    const float* b1 = (const float*)d_in[2];
    const float* w2 = (const float*)d_in[3];
    const float* b2 = (const float*)d_in[4];
    const float* w3 = (const float*)d_in[5];
    const float* b3 = (const float*)d_in[6];
    const float* w4 = (const float*)d_in[7];
    const float* b4 = (const float*)d_in[8];
    float* out = (float*)d_out;

    // xp planes live in d_out's first 32MB (dead before k_m2 overwrites d_out)
    unsigned short* xph = (unsigned short*)d_out;          // 16 MB
    unsigned short* xpl = xph + 8388608L;                  // 16 MB

    char* p = (char*)d_ws;
    uint32_t* c1p = (uint32_t*)p;  p += 16777216L * 4;     // 64 MB packed hi|lo
    short* Bh  = (short*)p;  p += 294912L * 2;
    short* Bl  = (short*)p;  p += 294912L * 2;
    float* gpart = (float*)p; p += 262144L * 4;
    float* scale = (float*)p; p += 4096L * 4;
    float* ga    = (float*)p; p += 4096L * 4;
    float* n_g   = (float*)p; p += 16L * 4;
    float* r1    = (float*)p; p += 65536L * 4;
    float* tmat4 = (float*)p; p += 262144L * 4;
    float* Uf    = (float*)p; p += 65536L * 4;
    float* Dpart = (float*)p; p += 256L * 4;

    k_xpack <<<4096, 256, 0, stream>>>(x, xph, xpl);
    k_wpack <<<1152, 256, 0, stream>>>(w1, Bh, Bl);
    k_conv1 <<<256,  512, 0, stream>>>(xph, xpl, Bh, Bl, b1, c1p, gpart);
    k_mlp   <<<16,   256, 0, stream>>>(gpart, b1, w2, b2, w3, b3, scale, ga, n_g);
    k_cos   <<<1024, 256, 0, stream>>>(c1p, scale, ga, n_g, r1);
    k_u     <<<256,  256, 0, stream>>>(r1, w4, b4, Uf, Dpart);
    k_t2    <<<1024, 256, 0, stream>>>(c1p, Uf, scale, Dpart, tmat4);
    k_m2    <<<2048, 256, 0, stream>>>(tmat4, r1, out);
}

// Round 18
// 208.496 us; speedup vs baseline: 1.5731x; 1.5731x over previous
//
#include <hip/hip_runtime.h>

#define EPSF 1e-8f

typedef __attribute__((ext_vector_type(8))) short bf16x8;
typedef __attribute__((ext_vector_type(16))) float f32x16;

#define MFMA32(a, b, c) __builtin_amdgcn_mfma_f32_32x32x16_bf16(a, b, c, 0, 0, 0)

// split f32 into (hi bf16 | lo bf16) packed in one u32: low16 = hi-part, high16 = lo-part
__device__ __forceinline__ uint32_t splitpack(float v) {
    uint32_t u = __float_as_uint(v);
    uint32_t hb = (u + 0x7fffu + ((u >> 16) & 1u)) & 0xffff0000u;  // RNE bf16 of v (f32 bits)
    float rem = v - __uint_as_float(hb);
    uint32_t r = __float_as_uint(rem);
    uint32_t lb = (r + 0x7fffu + ((r >> 16) & 1u)) >> 16;          // RNE bf16 of remainder
    return (hb >> 16) | (lb << 16);
}
__device__ __forceinline__ float unpackf(uint32_t p) {
    return __uint_as_float(p << 16) + __uint_as_float(p & 0xffff0000u);
}

// async global->LDS, 16B per lane; dst passed per-lane (base + lane*16) consistent with HW.
__device__ __forceinline__ void gload_lds16(const void* src, void* dst) {
#if __has_builtin(__builtin_amdgcn_global_load_lds)
    __builtin_amdgcn_global_load_lds(
        (const __attribute__((address_space(1))) uint32_t*)src,
        (__attribute__((address_space(3))) uint32_t*)dst, 16, 0, 0);
#else
    *(uint4*)dst = *(const uint4*)src;
#endif
}

// ---------- fused prep: x -> hi/lo bf16 planes (blocks 0..4095) ; w1 -> B-frag packs ----------
// xph/xpl index: (((b*16 + cg)*64 + h)*64 + w)*8 + j   (cg = c/8, j = c%8)
// w1 pack (blocks 4096..5247): [tap9][cp8][ntile8][lane64][j8]
__global__ __launch_bounds__(256) void k_prep(const float* __restrict__ x,
                                              const float* __restrict__ w1,
                                              unsigned short* __restrict__ xph,
                                              unsigned short* __restrict__ xpl,
                                              short* __restrict__ Bh, short* __restrict__ Bl) {
    const int bx = blockIdx.x;
    const int tid = threadIdx.x;
    if (bx < 4096) {                           // xpack: 4096 = b16 * cg16 * hb16
        const int hb = bx & 15, cg = (bx >> 4) & 15, b = bx >> 8;
        const int w = tid & 63, hs = tid >> 6;
        const int h = hb * 4 + hs;
        uint32_t hiw[4], low[4];
#pragma unroll
        for (int q = 0; q < 4; ++q) {
            uint32_t u0 = splitpack(x[(((b * 128 + cg * 8 + q * 2) * 64) + h) * 64 + w]);
            uint32_t u1 = splitpack(x[(((b * 128 + cg * 8 + q * 2 + 1) * 64) + h) * 64 + w]);
            hiw[q] = (u0 & 0xffffu) | (u1 << 16);
            low[q] = (u0 >> 16) | (u1 & 0xffff0000u);
        }
        const long o = ((((long)(b * 16 + cg) * 64 + h) * 64) + w) * 8;
        *(uint4*)(xph + o) = *(uint4*)hiw;
        *(uint4*)(xpl + o) = *(uint4*)low;
    } else {                                   // wpack: 1152 blocks over 294912 elems
        int d = (bx - 4096) * 256 + tid;
        int j = d & 7, lane = (d >> 3) & 63, nt = (d >> 9) & 7, cp = (d >> 12) & 7, tap = d >> 15;
        int oc = nt * 32 + (lane & 31);
        int cin = cp * 16 + (lane >> 5) * 8 + j;
        uint32_t u = splitpack(w1[oc * 1152 + cin * 9 + tap]);
        Bh[d] = (short)(u & 0xffffu);
        Bl[d] = (short)(u >> 16);
    }
}

// ---------- conv1: 3x3 SAME, bf16x3 via 32x32x16 MFMA (r14 proven config) ----------
// block: 512 thr = 8 waves (4 mq x 2 nh); tile 256 pixels (4h x 64w) x 128 oc.
// 1 block/CU low-traffic regime. A 2-buf (tap+1 ds_read prefetch) + B 4-buf.
// B buffer lifecycle (bufs free after taps 5,6,7,8 resp.): taps<5 reload same buf
// with tap+4; taps 5..7 load next-cp taps 1..3 into bufs 1..3; tap 8 loads next-cp
// tap 0 into buf 0 (short lead — one exposed load per cp, ~4%).
// XCD-contiguous remap. LDS: 2buf x 2plane x 12units x 66wl x 16B = 50688 B.
__global__ __launch_bounds__(512, 2) void k_conv1(
        const unsigned short* __restrict__ xph, const unsigned short* __restrict__ xpl,
        const short* __restrict__ Bh, const short* __restrict__ Bl,
        const float* __restrict__ b1,
        uint32_t* __restrict__ c1p, float* __restrict__ gpart) {
    __shared__ uint4 lds[2 * 2 * 12 * 66];
    const int bxr = blockIdx.x;                // 512; remap so XCD k gets [k*64,(k+1)*64)
    const int bx = ((bxr & 7) << 6) | (bxr >> 3);
    const int ot = bx & 1, hp = (bx >> 1) & 15, b = bx >> 5;
    const int h0 = hp * 4;
    const int tid = threadIdx.x;
    const int lane = tid & 63, wv = tid >> 6;
    const int mq = wv >> 1, nh = wv & 1;
    const int l31 = lane & 31, hbit = lane >> 5;

    f32x16 acc[2][2];
#pragma unroll
    for (int i = 0; i < 2; ++i)
#pragma unroll
        for (int j = 0; j < 2; ++j)
#pragma unroll
            for (int r = 0; r < 16; ++r) acc[i][j][r] = 0.f;

    auto stage = [&](int buf, int cp) {
#pragma unroll
        for (int i = 0; i < 3; ++i) {
            const int id = wv * 3 + i;              // 0..23
            const int plane = (id >= 12) ? 1 : 0;
            const int u = id - plane * 12;          // 0..11
            const int r6 = u >> 1, kg = u & 1;
            const int grow = h0 - 1 + r6;
            uint4* dst = &lds[((buf * 2 + plane) * 12 + u) * 66 + 1 + lane];
            if ((unsigned)grow < 64u) {
                const unsigned short* pls = plane ? xpl : xph;
                const unsigned short* src =
                    pls + ((((long)(b * 16 + cp * 2 + kg) * 64 + grow) * 64) + lane) * 8;
                gload_lds16(src, dst);
            } else {
                *dst = (uint4){0u, 0u, 0u, 0u};
            }
        }
    };

    stage(0, 0);
    if (tid < 96) {   // halo zeros (wl = 0, 65) for all buf/plane/units
        const int row = tid >> 1, side = tid & 1;
        lds[row * 66 + (side ? 65 : 0)] = (uint4){0u, 0u, 0u, 0u};
    }
    __syncthreads();

    bf16x8 Ahv[2][2], Alv[2][2], Bhv[4][2], Blv[4][2];
#define LOADA(tap_, par) do {                                                     \
        const int kh_ = (tap_) / 3, kw_ = (tap_) % 3;                             \
        _Pragma("unroll")                                                         \
        for (int mt = 0; mt < 2; ++mt) {                                          \
            const int rb = ((buf * 2 + 0) * 12 + (mq + kh_) * 2 + hbit) * 66      \
                           + kw_ + mt * 32 + l31;                                 \
            Ahv[par][mt] = *(const bf16x8*)&lds[rb];                              \
            Alv[par][mt] = *(const bf16x8*)&lds[rb + 12 * 66];                    \
        } } while (0)
#define LOADB(cp_, tap_, par) do {                                                \
        _Pragma("unroll")                                                         \
        for (int nt = 0; nt < 2; ++nt) {                                          \
            const int fi = (((tap_) * 8 + (cp_)) * 8 + ot * 4 + nh * 2 + nt) * 512 + lane * 8; \
            Bhv[par][nt] = *(const bf16x8*)(Bh + fi);                             \
            Blv[par][nt] = *(const bf16x8*)(Bl + fi);                             \
        } } while (0)

    // prologue: B taps 0..3 of cp0 into bufs 0..3
    LOADB(0, 0, 0);
    LOADB(0, 1, 1);
    LOADB(0, 2, 2);
    LOADB(0, 3, 3);
    int buf = 0;
    for (int cp = 0; cp < 8; ++cp) {
        if (cp < 7) stage(buf ^ 1, cp + 1);
        LOADA(0, 0);
#pragma unroll
        for (int tap = 0; tap < 9; ++tap) {
            if (tap < 8) LOADA(tap + 1, (tap + 1) & 1);   // A prefetch (different buf, safe)
            const int ab = tap & 1, bb = tap & 3;
            __builtin_amdgcn_s_setprio(1);
#pragma unroll
            for (int nt = 0; nt < 2; ++nt)
#pragma unroll
                for (int mt = 0; mt < 2; ++mt) {
                    acc[mt][nt] = MFMA32(Ahv[ab][mt], Bhv[bb][nt], acc[mt][nt]);
                    acc[mt][nt] = MFMA32(Ahv[ab][mt], Blv[bb][nt], acc[mt][nt]);
                    acc[mt][nt] = MFMA32(Alv[ab][mt], Bhv[bb][nt], acc[mt][nt]);
                }
            __builtin_amdgcn_s_setprio(0);
            // B reload AFTER consumption; buf free times: b1@t5 b2@t6 b3@t7 b0@t8
            if (tap < 5) {
                LOADB(cp, tap + 4, tap & 3);
            } else if (cp < 7) {
                if (tap < 8) {
                    LOADB(cp + 1, tap - 4, (tap - 4) & 3);   // taps 1..3 -> bufs 1..3
                } else {
                    LOADB(cp + 1, 0, 0);                     // tap 0 -> buf 0 (short lead)
                }
            }
        }
        __syncthreads();
        buf ^= 1;
    }
#undef LOADA
#undef LOADB

    const int hrow = h0 + mq;
#pragma unroll
    for (int nt = 0; nt < 2; ++nt) {
        const int oc = ot * 128 + (nh * 2 + nt) * 32 + l31;
        float g = 0.f;
#pragma unroll
        for (int mt = 0; mt < 2; ++mt)
#pragma unroll
            for (int r = 0; r < 16; ++r) g += acc[mt][nt][r];
        g += __shfl_xor(g, 32);
        if (hbit == 0) gpart[((b * 16 + hp) * 4 + mq) * 256 + oc] = g;
        const float bias = b1[oc];
#pragma unroll
        for (int mt = 0; mt < 2; ++mt) {
#pragma unroll
            for (int r = 0; r < 16; ++r) {
                const int row = (r & 3) + 8 * (r >> 2) + 4 * hbit;
                const int p = hrow * 64 + mt * 32 + row;
                c1p[((long)(b * 4096 + p)) * 256 + oc] = splitpack(acc[mt][nt][r] + bias);
            }
        }
    }
}

// ---------- tiny MLP chain: sum gap partials, c2, c3 -> scale, ga, n_g ----------
__global__ __launch_bounds__(256) void k_mlp(const float* __restrict__ gpart,
                                             const float* __restrict__ b1,
                                             const float* __restrict__ w2, const float* __restrict__ b2,
                                             const float* __restrict__ w3, const float* __restrict__ b3,
                                             float* __restrict__ scale, float* __restrict__ ga,
                                             float* __restrict__ n_g) {
    int b = blockIdx.x, tid = threadIdx.x;
    __shared__ float gs[256], c2s[256], red[4];
    float g = 0.f;
#pragma unroll 8
    for (int i = 0; i < 64; ++i) g += gpart[(b * 64 + i) * 256 + tid];
    gs[tid] = g * (1.f / 4096.f) + b1[tid];
    __syncthreads();
    {
        const float4* wr = (const float4*)(w2 + tid * 256);
        float a = b2[tid];
#pragma unroll 8
        for (int c4 = 0; c4 < 64; c4++) {
            float4 wv = wr[c4];
            a += wv.x * gs[c4*4] + wv.y * gs[c4*4+1] + wv.z * gs[c4*4+2] + wv.w * gs[c4*4+3];
        }
        c2s[tid] = a;
    }
    __syncthreads();
    float a3 = b3[tid];
    {
        const float4* wr = (const float4*)(w3 + tid * 256);
#pragma unroll 8
        for (int c4 = 0; c4 < 64; c4++) {
            float4 wv = wr[c4];
            a3 += wv.x * c2s[c4*4] + wv.y * c2s[c4*4+1] + wv.z * c2s[c4*4+2] + wv.w * c2s[c4*4+3];
        }
    }
    float s1 = 1.f + a3;
    float g2 = gs[tid] * s1;
    scale[b * 256 + tid] = s1;
    ga[b * 256 + tid] = g2 * s1;
    float r = g2 * g2;
    for (int off = 32; off; off >>= 1) r += __shfl_down(r, off);
    if ((tid & 63) == 0) red[tid >> 6] = r;
    __syncthreads();
    if (tid == 0) n_g[b] = fmaxf(sqrtf(red[0] + red[1] + red[2] + red[3]), EPSF);
}

// ---------- cos -> r1[b][p], packed NHWC reads, 32-lane reduce per pixel ----------
__global__ __launch_bounds__(256) void k_cos(
        const uint32_t* __restrict__ c1p,
        const float* __restrict__ scale, const float* __restrict__ ga,
        const float* __restrict__ n_g, float* __restrict__ r1) {
    const int bx = blockIdx.x;                 // 1024 = b16 * pt64
    const int pt = bx & 63, b = bx >> 6;
    const int tid = threadIdx.x;
    const int lane = tid & 63, wv = tid >> 6;
    const int half = lane >> 5, l31 = lane & 31;
    float ga8[8], sc8[8];
#pragma unroll
    for (int q = 0; q < 8; ++q) {
        ga8[q] = ga[b * 256 + l31 * 8 + q];
        sc8[q] = scale[b * 256 + l31 * 8 + q];
    }
    const float ng = n_g[b];
#pragma unroll
    for (int pp = 0; pp < 8; ++pp) {
        const int p = pt * 64 + wv * 16 + pp * 2 + half;
        const uint32_t* base = c1p + ((long)(b * 4096 + p)) * 256 + l31 * 8;
        uint4 a = *(const uint4*)base;
        uint4 bq = *(const uint4*)(base + 4);
        uint32_t pk[8] = {a.x, a.y, a.z, a.w, bq.x, bq.y, bq.z, bq.w};
        float num = 0.f, den = 0.f;
#pragma unroll
        for (int q = 0; q < 8; ++q) {
            const float v = unpackf(pk[q]);
            num += ga8[q] * v;
            const float t = sc8[q] * v;
            den += t * t;
        }
#pragma unroll
        for (int off = 1; off <= 16; off <<= 1) {
            num += __shfl_xor(num, off);
            den += __shfl_xor(den, off);
        }
        if (l31 == 0) {
            float na = fmaxf(sqrtf(den), EPSF);
            r1[b * 4096 + p] = num / (ng * na);
        }
    }
}

// ---------- U-factor: Uf[b'][pr*256+k] = sum_o w4[o][k]*r1[b'][pr*256+o]; Dpart[b'*16+pr] ----------
__global__ __launch_bounds__(256) void k_u(const float* __restrict__ r1,
                                           const float* __restrict__ w4,
                                           const float* __restrict__ b4,
                                           float* __restrict__ Uf, float* __restrict__ Dpart) {
    const int g = blockIdx.x;                  // 256 = b'16 * pr16
    const int tid = threadIdx.x;
    __shared__ float rs[256], red[4];
    rs[tid] = r1[(g >> 4) * 4096 + (g & 15) * 256 + tid];
    __syncthreads();
    float a = 0.f;
#pragma unroll 8
    for (int o = 0; o < 256; ++o) a += rs[o] * w4[o * 256 + tid];
    Uf[(g >> 4) * 4096 + (g & 15) * 256 + tid] = a;
    float d = b4[tid] * rs[tid];
    for (int off = 32; off; off >>= 1) d += __shfl_down(d, off);
    if ((tid & 63) == 0) red[tid >> 6] = d;
    __syncthreads();
    if (tid == 0) Dpart[g] = red[0] + red[1] + red[2] + red[3];
}

// ---------- t slice: tmat4[kc][b][i][b'] = sum_{jc in kc} c1s[b][i][jj]*Uf[b'][jj] (+D on kc0) ----------
// split-K x4 for occupancy: 1024 blocks (4/CU) instead of 256.
__global__ __launch_bounds__(256) void k_t2(const uint32_t* __restrict__ c1p,
                                            const float* __restrict__ Uf,
                                            const float* __restrict__ scale,
                                            const float* __restrict__ Dpart,
                                            float* __restrict__ tmat4) {
    __shared__ float Ac[16][256];
    __shared__ float Bc[16][260];
    __shared__ float scs[256];
    const int bx = blockIdx.x;                 // 1024 = kc4 * b16 * it16
    const int kc = bx >> 8;
    const int b = (bx >> 4) & 15, it = bx & 15;
    const int tid = threadIdx.x;
    const int il = tid >> 4, bp = tid & 15;
    scs[tid] = scale[b * 256 + tid];
    float acc = 0.f;
    for (int jc = kc * 4; jc < kc * 4 + 4; ++jc) {   // chunk: pr = jc, k in [0,256)
        __syncthreads();
#pragma unroll
        for (int q = 0; q < 4; ++q) {
            const int f4i = tid + q * 256;
            const int row = f4i >> 6, col4 = f4i & 63;
            uint4 u = *(const uint4*)(c1p +
                ((long)(b * 4096 + it * 256 + row * 16 + jc)) * 256 + col4 * 4);
            Ac[row][col4 * 4 + 0] = unpackf(u.x) * scs[col4 * 4 + 0];
            Ac[row][col4 * 4 + 1] = unpackf(u.y) * scs[col4 * 4 + 1];
            Ac[row][col4 * 4 + 2] = unpackf(u.z) * scs[col4 * 4 + 2];
            Ac[row][col4 * 4 + 3] = unpackf(u.w) * scs[col4 * 4 + 3];
            *(float4*)&Bc[row][col4 * 4] =
                *(const float4*)(Uf + (long)row * 4096 + jc * 256 + col4 * 4);
        }
        __syncthreads();
#pragma unroll 8
        for (int j = 0; j < 256; j += 4) {
            float4 a4  = *(const float4*)&Ac[il][j];
            float4 b4v = *(const float4*)&Bc[bp][j];
            acc += a4.x * b4v.x + a4.y * b4v.y + a4.z * b4v.z + a4.w * b4v.w;
        }
    }
    if (kc == 0) {
        float D = 0.f;
#pragma unroll
        for (int pr = 0; pr < 16; ++pr) D += Dpart[bp * 16 + pr];
        acc += D;
    }
    tmat4[kc * 65536 + ((b * 256) + it * 16 + il) * 16 + bp] = acc;
}

// ---------- m2[b][i][p] = sum_b' t[b][i][b'] * r1[b'][p]  (writes d_out) ----------
__global__ __launch_bounds__(256) void k_m2(const float* __restrict__ tmat4,
                                            const float* __restrict__ r1,
                                            float* __restrict__ outb) {
    __shared__ float r1s[16][512];
    __shared__ float ts[256];
    int bx = blockIdx.x;
    int b = bx >> 7, it = (bx >> 3) & 15, pc = bx & 7;
    int tid = threadIdx.x;
    {
        const int idx = (b * 256 + it * 16) * 16 + tid;
        ts[tid] = tmat4[idx] + tmat4[65536 + idx] + tmat4[131072 + idx] + tmat4[196608 + idx];
    }
#pragma unroll
    for (int k = 0; k < 8; k++) {
        int f4i = tid + k * 256;
        int row = f4i >> 7, col = f4i & 127;
        *(float4*)&r1s[row][col * 4] = *(const float4*)(r1 + ((long)row << 12) + pc * 512 + col * 4);
    }
    __syncthreads();
    for (int il = 0; il < 16; il++) {
        float tv[16];
#pragma unroll
        for (int bp = 0; bp < 16; bp++) tv[bp] = ts[il * 16 + bp];
#pragma unroll
        for (int k = 0; k < 2; k++) {
            int p = k * 256 + tid;
            float s = 0.f;
#pragma unroll
            for (int bp = 0; bp < 16; bp++) s += tv[bp] * r1s[bp][p];
            outb[((long)b << 20) + ((long)(it * 16 + il) << 12) + pc * 512 + p] = s;
        }
    }
}

extern "C" void kernel_launch(void* const* d_in, const int* in_sizes, int n_in,
                              void* d_out, int out_size, void* d_ws, size_t ws_size,
                              hipStream_t stream) {
    const float* x  = (const float*)d_in[0];
    const float* w1 = (const float*)d_in[1];
    const float* b1 = (const float*)d_in[2];
    const float* w2 = (const float*)d_in[3];
    const float* b2 = (const float*)d_in[4];
    const float* w3 = (const float*)d_in[5];
    const float* b3 = (const float*)d_in[6];
    const float* w4 = (const float*)d_in[7];
    const float* b4 = (const float*)d_in[8];
    float* out = (float*)d_out;

    // xp planes live in d_out's first 32MB (dead before k_m2 overwrites d_out)
    unsigned short* xph = (unsigned short*)d_out;          // 16 MB
    unsigned short* xpl = xph + 8388608L;                  // 16 MB

    char* p = (char*)d_ws;
    uint32_t* c1p = (uint32_t*)p;  p += 16777216L * 4;     // 64 MB packed hi|lo
    short* Bh  = (short*)p;  p += 294912L * 2;
    short* Bl  = (short*)p;  p += 294912L * 2;
    float* gpart = (float*)p; p += 262144L * 4;
    float* scale = (float*)p; p += 4096L * 4;
    float* ga    = (float*)p; p += 4096L * 4;
    float* n_g   = (float*)p; p += 16L * 4;
    float* r1    = (float*)p; p += 65536L * 4;
    float* tmat4 = (float*)p; p += 262144L * 4;
    float* Uf    = (float*)p; p += 65536L * 4;
    float* Dpart = (float*)p; p += 256L * 4;

    k_prep  <<<5248, 256, 0, stream>>>(x, w1, xph, xpl, Bh, Bl);
    k_conv1 <<<512,  512, 0, stream>>>(xph, xpl, Bh, Bl, b1, c1p, gpart);
    k_mlp   <<<16,   256, 0, stream>>>(gpart, b1, w2, b2, w3, b3, scale, ga, n_g);
    k_cos   <<<1024, 256, 0, stream>>>(c1p, scale, ga, n_g, r1);
    k_u     <<<256,  256, 0, stream>>>(r1, w4, b4, Uf, Dpart);
    k_t2    <<<1024, 256, 0, stream>>>(c1p, Uf, scale, Dpart, tmat4);
    k_m2    <<<2048, 256, 0, stream>>>(tmat4, r1, out);
}